// Round 4
// baseline (3027.061 us; speedup 1.0000x reference)
//
#include <hip/hip_runtime.h>
#include <hip/hip_bf16.h>
#include <stdint.h>

#define T_SEQ 2048
#define DDIM 256
#define G3 768
#define NB 64
#define NQR 10

typedef _Float16 h2f __attribute__((ext_vector_type(2)));
typedef _Float16 f16x8 __attribute__((ext_vector_type(8)));
typedef float f32x4 __attribute__((ext_vector_type(4)));
typedef unsigned u32x4 __attribute__((ext_vector_type(4)));

__device__ __forceinline__ unsigned packf16(float a, float b) {
    auto p = __builtin_amdgcn_cvt_pkrtz(a, b);   // __fp16 ext_vector(2)
    return __builtin_bit_cast(unsigned, p);
}
__device__ __forceinline__ float sigmf(float x) { return 1.0f / (1.0f + __expf(-x)); }
__device__ __forceinline__ float tanhff(float x) {
    float ax = fabsf(x);
    float e = __expf(2.0f * ax);
    float t = 1.0f - 2.0f / (e + 1.0f);
    return copysignf(t, x);
}

// ---------------- prologue: span selection + wcol + bsum ----------------
__global__ __launch_bounds__(256) void k_prologue(
    const float* __restrict__ logits, const float* __restrict__ spans,
    const float* __restrict__ W_sal, const float* __restrict__ b_sal,
    int* __restrict__ meta, float* __restrict__ wcol, float* __restrict__ bsum) {
    int tid = threadIdx.x;
    if (tid < NB) {
        int b = tid;
        float bestv = -1e30f; int best = 0;
        for (int q = 0; q < NQR; ++q) {
            float l0 = logits[(b * NQR + q) * 2 + 0];
            float l1 = logits[(b * NQR + q) * 2 + 1];
            float sc = sigmf(l0 - l1);   // monotone in softmax[...,0]
            if (sc > bestv) { bestv = sc; best = q; }
        }
        float cx = spans[(b * NQR + best) * 2 + 0];
        float w  = spans[(b * NQR + best) * 2 + 1];
        float x0 = (cx - 0.5f * w) * (float)(T_SEQ * 2);
        float x1 = (cx + 0.5f * w) * (float)(T_SEQ * 2);
        int se0 = (int)floorf(x0 * 0.5f);
        int se1 = (int)floorf(x1 * 0.5f);
        int start = min(max(se0, 0), T_SEQ - 1);
        int end_eff = min(se1, T_SEQ - 1);
        int len = end_eff - start + 1;
        if (len < 0) len = 0;
        meta[b] = start; meta[NB + b] = len;
    }
    float acc = 0.f;
    for (int e = 0; e < DDIM; ++e) acc += W_sal[e * DDIM + tid];
    wcol[tid] = acc;
    if (tid < 64) {
        float p = b_sal[tid] + b_sal[tid + 64] + b_sal[tid + 128] + b_sal[tid + 192];
        for (int off = 32; off; off >>= 1) p += __shfl_down(p, off, 64);
        if (tid == 0) *bsum = p;
    }
}

// ---------------- prep: transpose W_ih ----------------
__global__ __launch_bounds__(256) void k_prep(
    const float* __restrict__ W_ih, float* __restrict__ wt_ih) {
    int g = blockIdx.x, k = threadIdx.x;
    wt_ih[k * G3 + g] = W_ih[g * DDIM + k];
}

// ---------------- prep2: W_hh -> MFMA B-fragments (f16 packed) ----------------
// frag id f = wt*8 + kc  (wt = w*6 + t6 in [0,48)); per lane l, jj in [0,4):
//   B[k][col] with col = wt*16 + (l&15), k = kc*32 + (l>>4)*8 + jj*2 (+1 in hi half)
__global__ __launch_bounds__(256) void k_prep2(
    const float* __restrict__ W_hh, unsigned* __restrict__ wfrag) {
    int u = blockIdx.x * 256 + threadIdx.x;     // 98304 total
    int jj = u & 3;
    int l  = (u >> 2) & 63;
    int kc = (u >> 8) & 7;
    int wt = u >> 11;
    int col = wt * 16 + (l & 15);
    int k = kc * 32 + ((l >> 4) << 3) + jj * 2;
    wfrag[u] = packf16(W_hh[col * DDIM + k], W_hh[col * DDIM + k + 1]);
}

// ---------------- gi GEMM: gi[b,t,g] = sliced[b,t,:]@W_ih[g,:] + b_ih ----------------
__global__ __launch_bounds__(256) void k_gemm(
    const float* __restrict__ src_vid, const float* __restrict__ wt_ih,
    const float* __restrict__ b_ih, const int* __restrict__ meta,
    float* __restrict__ gi, int t0, int tc, int TC) {
    int b = blockIdx.y;
    int len = meta[NB + b];
    int tb = t0 + blockIdx.x * 16;
    int tcap = t0 + tc; if (tcap > len) tcap = len;
    if (tb >= tcap) return;
    int start = meta[b];
    int j = threadIdx.x;
    int nval = tcap - tb; if (nval > 16) nval = 16;
    float aR[16], aZ[16], aN[16];
    float bR = b_ih[j], bZ = b_ih[DDIM + j], bN = b_ih[2 * DDIM + j];
#pragma unroll
    for (int r = 0; r < 16; ++r) { aR[r] = bR; aZ[r] = bZ; aN[r] = bN; }
    const float* xb = src_vid + ((size_t)b * T_SEQ + start + tb) * DDIM;
    for (int kq = 0; kq < 64; ++kq) {
        float4 xq[16];
#pragma unroll
        for (int r = 0; r < 16; ++r) {
            if (r < nval) xq[r] = *(const float4*)(xb + r * DDIM + kq * 4);
            else          xq[r] = make_float4(0.f, 0.f, 0.f, 0.f);
        }
#pragma unroll
        for (int e = 0; e < 4; ++e) {
            int k = kq * 4 + e;
            float wR = wt_ih[k * G3 + j];
            float wZ = wt_ih[k * G3 + DDIM + j];
            float wN = wt_ih[k * G3 + 2 * DDIM + j];
#pragma unroll
            for (int r = 0; r < 16; ++r) {
                float xv = (e == 0) ? xq[r].x : (e == 1) ? xq[r].y : (e == 2) ? xq[r].z : xq[r].w;
                aR[r] = fmaf(xv, wR, aR[r]);
                aZ[r] = fmaf(xv, wZ, aZ[r]);
                aN[r] = fmaf(xv, wN, aN[r]);
            }
        }
    }
    float* go = gi + ((size_t)b * TC + (tb - t0)) * G3;
    for (int r = 0; r < nval; ++r) {
        go[r * G3 + j] = aR[r];
        go[r * G3 + DDIM + j] = aZ[r];
        go[r * G3 + 2 * DDIM + j] = aN[r];
    }
}

// ---------------- GRU recurrence (MFMA matvec) ----------------
// One block per batch, 512 threads = 8 waves. Wave w owns 6 col-tiles of 16
// (cols [w*96, w*96+96)). B-frags (48 x u32x4 = 192 regs) stay in AGPRs --
// MFMA reads them directly, no accvgpr_read tax. A = h replicated across all
// 16 rows (row mapping of A thus irrelevant), built from packed-f16 h in LDS.
__global__ void __launch_bounds__(512)
__attribute__((amdgpu_waves_per_eu(2, 2))) k_gru(
    const float* __restrict__ gi, const unsigned* __restrict__ wfrag,
    const float* __restrict__ b_ih, const float* __restrict__ b_hh,
    const int* __restrict__ meta, float* __restrict__ h_state,
    int t0, int t1, int TC) {
    int b = blockIdx.x, tid = threadIdx.x;
    int lane = tid & 63, w = tid >> 6;
    int len = meta[NB + b];

    // resident weight fragments (coalesced 16B/lane loads)
    u32x4 bf[48];
    const u32x4* wfr = (const u32x4*)wfrag;
#pragma unroll
    for (int t6 = 0; t6 < 6; ++t6)
#pragma unroll
        for (int kc = 0; kc < 8; ++kc)
            bf[t6 * 8 + kc] = wfr[((w * 6 + t6) * 8 + kc) * 64 + lane];

    int c = tid & 255;   // finalize column (valid when tid<256)
    float biR = b_ih[c], biZ = b_ih[256 + c], biN = b_ih[512 + c];
    float bhR = b_hh[c], bhZ = b_hh[256 + c], bhN = b_hh[512 + c];

    __shared__ unsigned hl[128];   // packed f16 h
    __shared__ float pl[768];      // matvec outputs

    float h = 0.f;
    if (tid < 256) {
        if (t0 != 0) h = h_state[b * DDIM + c];
        float hp = __shfl_xor(h, 1, 64);
        if (!(c & 1)) hl[c >> 1] = packf16(h, hp);
    }

    const float* gbase = gi + (size_t)b * TC * G3;
    float gR = biR, gZ = biZ, gN = biN;
    if (tid < 256 && t0 < t1 && t0 < len) {
        const float* gp = gbase + c;
        gR = gp[0]; gZ = gp[DDIM]; gN = gp[2 * DDIM];
    }
    __syncthreads();

    const f32x4 zf = {0.f, 0.f, 0.f, 0.f};
    for (int t = t0; t < t1; ++t) {
        // prefetch next-step gi (hides under MFMA phase)
        float nR = biR, nZ = biZ, nN = biN;
        int tn = t + 1;
        if (tid < 256 && tn < t1 && tn < len) {
            const float* gp = gbase + (size_t)(tn - t0) * G3 + c;
            nR = gp[0]; nZ = gp[DDIM]; nN = gp[2 * DDIM];
        }
        // matvec: out[col] = sum_k h[k] * W_hh[col][k]
        f32x4 cf[6];
        const u32x4* hb = (const u32x4*)hl;
#pragma unroll
        for (int kc = 0; kc < 8; ++kc) {
            u32x4 av = hb[kc * 4 + (lane >> 4)];
            f16x8 af = __builtin_bit_cast(f16x8, av);
#pragma unroll
            for (int t6 = 0; t6 < 6; ++t6) {
                cf[t6] = __builtin_amdgcn_mfma_f32_16x16x32_f16(
                    af, __builtin_bit_cast(f16x8, bf[t6 * 8 + kc]),
                    (kc == 0) ? zf : cf[t6], 0, 0, 0);
            }
        }
        if (lane < 16) {
#pragma unroll
            for (int t6 = 0; t6 < 6; ++t6)
                pl[(w * 6 + t6) * 16 + lane] = cf[t6][0];
        }
        __syncthreads();
        if (tid < 256) {
            float hr = pl[c] + bhR;
            float hz = pl[256 + c] + bhZ;
            float hn = pl[512 + c] + bhN;
            float r = sigmf(gR + hr);
            float z = sigmf(gZ + hz);
            float n = tanhff(gN + r * hn);
            h = (1.0f - z) * n + z * h;
            float hp = __shfl_xor(h, 1, 64);
            if (!(c & 1)) hl[c >> 1] = packf16(h, hp);
        }
        gR = nR; gZ = nZ; gN = nN;
        __syncthreads();
    }
    if (tid < 256) h_state[b * DDIM + c] = h;
}

// ---------------- epilogue: saliency = ((1+h·src)·(mem·wcol)+bsum)/16 ----------------
__global__ __launch_bounds__(256) void k_epi(
    const float* __restrict__ memory, const float* __restrict__ src_vid,
    const float* __restrict__ h_state, const float* __restrict__ wcol,
    const float* __restrict__ bsum, float* __restrict__ out) {
    int wid = blockIdx.x * 4 + (threadIdx.x >> 6);
    int lane = threadIdx.x & 63;
    int b = wid >> 11;
    int t = wid & 2047;
    const float4* mp = (const float4*)(memory + ((size_t)b * T_SEQ + t) * DDIM);
    const float4* sp = (const float4*)(src_vid + ((size_t)b * T_SEQ + t) * DDIM);
    const float4* hp = (const float4*)(h_state + b * DDIM);
    const float4* wp = (const float4*)wcol;
    float4 m = mp[lane], s = sp[lane], hv = hp[lane], wc = wp[lane];
    float s1 = m.x * wc.x + m.y * wc.y + m.z * wc.z + m.w * wc.w;
    float s2 = hv.x * s.x + hv.y * s.y + hv.z * s.z + hv.w * s.w;
    for (int off = 32; off; off >>= 1) {
        s1 += __shfl_down(s1, off, 64);
        s2 += __shfl_down(s2, off, 64);
    }
    if (lane == 0) out[(size_t)b * T_SEQ + t] = ((1.0f + s2) * s1 + *bsum) * 0.0625f;
}

extern "C" void kernel_launch(void* const* d_in, const int* in_sizes, int n_in,
                              void* d_out, int out_size, void* d_ws, size_t ws_size,
                              hipStream_t stream) {
    const float* logits  = (const float*)d_in[0];
    const float* spans   = (const float*)d_in[1];
    const float* memory  = (const float*)d_in[2];
    const float* src_vid = (const float*)d_in[3];
    const float* W_ih    = (const float*)d_in[4];
    const float* W_hh    = (const float*)d_in[5];
    const float* b_ih    = (const float*)d_in[6];
    const float* b_hh    = (const float*)d_in[7];
    const float* W_sal   = (const float*)d_in[8];
    const float* b_sal   = (const float*)d_in[9];
    float* out = (float*)d_out;
    char* ws = (char*)d_ws;

    const size_t OFF_META = 0;        // 128 ints
    const size_t OFF_WCOL = 1024;     // 256 f32
    const size_t OFF_BSUM = 2048;     // 1 f32
    const size_t OFF_H    = 4096;     // 64*256 f32 = 65536
    const size_t OFF_FRAG = 69632;    // 98304 u32 = 393216
    const size_t OFF_WTIH = 462848;   // 256*768 f32 = 786432
    const size_t OFF_GI   = 1249280;  // up to 64*2048*768 f32

    int* meta       = (int*)(ws + OFF_META);
    float* wcol     = (float*)(ws + OFF_WCOL);
    float* bsum     = (float*)(ws + OFF_BSUM);
    float* h_state  = (float*)(ws + OFF_H);
    unsigned* wfrag = (unsigned*)(ws + OFF_FRAG);
    float* wt_ih    = (float*)(ws + OFF_WTIH);
    float* gi       = (float*)(ws + OFF_GI);

    size_t gi_cap = (ws_size > OFF_GI) ? (ws_size - OFF_GI) : 0;
    long long tc_max = (long long)(gi_cap / ((size_t)NB * G3 * 4));
    int TC = (tc_max > T_SEQ) ? T_SEQ : (int)tc_max;
    if (TC < 1) TC = 1;

    k_prologue<<<dim3(1), dim3(256), 0, stream>>>(logits, spans, W_sal, b_sal, meta, wcol, bsum);
    k_prep<<<dim3(G3), dim3(256), 0, stream>>>(W_ih, wt_ih);
    k_prep2<<<dim3(384), dim3(256), 0, stream>>>(W_hh, wfrag);
    for (int t0 = 0; t0 < T_SEQ; t0 += TC) {
        int tc = T_SEQ - t0; if (tc > TC) tc = TC;
        k_gemm<<<dim3((tc + 15) / 16, NB), dim3(256), 0, stream>>>(
            src_vid, wt_ih, b_ih, meta, gi, t0, tc, TC);
        k_gru<<<dim3(NB), dim3(512), 0, stream>>>(
            gi, wfrag, b_ih, b_hh, meta, h_state, t0, t0 + tc, TC);
    }
    k_epi<<<dim3(NB * T_SEQ / 4), dim3(256), 0, stream>>>(
        memory, src_vid, h_state, wcol, bsum, out);
}